// Round 8
// baseline (189.457 us; speedup 1.0000x reference)
//
#include <hip/hip_runtime.h>
#include <hip/hip_bf16.h>

#define D          64
#define N_ROWS     131072
#define TOTAL_ELEM (N_ROWS * D)      // 8388608
#define RPB        128               // rows per block
#define ITERS      (RPB / 16)        // 8
#define NBLK       (N_ROWS / RPB)    // 1024

typedef __attribute__((ext_vector_type(4))) float f32x4;
typedef __attribute__((ext_vector_type(8))) short bf16x8;

// pack two fp32 -> two bf16 (truncation) in one v_perm_b32
__device__ __forceinline__ unsigned pkbf(float lo, float hi) {
    return __builtin_amdgcn_perm(__float_as_uint(hi), __float_as_uint(lo), 0x07060302u);
}

// max with DPP-shifted copy (16-lane-row reduce, VALU pipe — no LDS traffic)
template <int CTRL>
__device__ __forceinline__ float dpp_max_step(float x) {
    int y = __builtin_amdgcn_update_dpp(0, __float_as_int(x), CTRL, 0xF, 0xF, false);
    return fmaxf(x, __int_as_float(y));
}

__global__ __launch_bounds__(512, 4)
void vq_kernel(const float* __restrict__ z, const float* __restrict__ cb,
               float* __restrict__ zq, float* __restrict__ lossp) {
    const int tid  = threadIdx.x;
    const int l    = tid & 63;
    const int w    = tid >> 6;      // wave 0..7 owns codes [w*128, w*128+128)
    const int col  = l & 15;
    const int krow = l >> 4;        // 0..3

    __shared__ float wbest[ITERS][8][16];   // [tile][wave][row] packed (score|idx)
    __shared__ float lossred[8];

    // ---- Phase 0: codebook -> register B-fragments + biases (-||e||^2/2) ----
    bf16x8 bfrag[8][2];
    float  bias[8];
    #pragma unroll
    for (int t = 0; t < 8; ++t) {
        const int code = (w * 8 + t) * 16 + col;
        const float* e = cb + code * D + krow * 8;
        f32x4 e0 = *(const f32x4*)(e);
        f32x4 e1 = *(const f32x4*)(e + 4);
        f32x4 e2 = *(const f32x4*)(e + 32);
        f32x4 e3 = *(const f32x4*)(e + 36);
        float np = 0.f;
        #pragma unroll
        for (int j = 0; j < 4; ++j) {
            np = fmaf(e0[j], e0[j], np); np = fmaf(e1[j], e1[j], np);
            np = fmaf(e2[j], e2[j], np); np = fmaf(e3[j], e3[j], np);
        }
        // sum the 4 lanes (l, l^16, l^32, l^48) holding this code's K-slices
        np += __shfl_xor(np, 16, 64);
        np += __shfl_xor(np, 32, 64);
        bias[t] = -0.5f * np;
        union { bf16x8 v; unsigned u[4]; } b0, b1;
        b0.u[0] = pkbf(e0[0], e0[1]); b0.u[1] = pkbf(e0[2], e0[3]);
        b0.u[2] = pkbf(e1[0], e1[1]); b0.u[3] = pkbf(e1[2], e1[3]);
        b1.u[0] = pkbf(e2[0], e2[1]); b1.u[1] = pkbf(e2[2], e2[3]);
        b1.u[2] = pkbf(e3[0], e3[1]); b1.u[3] = pkbf(e3[2], e3[3]);
        bfrag[t][0] = b0.v; bfrag[t][1] = b1.v;
    }

    const unsigned codebase = (unsigned)(w * 128 + col);

    // ---- Phase 1: scoring with 1-tile-ahead prefetch, NO barriers ----
    const size_t rowstride = (size_t)16 * D;
    const float* zbase = z + (size_t)(blockIdx.x * RPB + col) * D + krow * 8;
    f32x4 c0 = *(const f32x4*)(zbase);
    f32x4 c1 = *(const f32x4*)(zbase + 4);
    f32x4 c2 = *(const f32x4*)(zbase + 32);
    f32x4 c3 = *(const f32x4*)(zbase + 36);

    #pragma unroll 2
    for (int it = 0; it < ITERS; ++it) {
        // issue next tile's loads FIRST — latency hides under this tile's compute
        const int itn = (it + 1 < ITERS) ? it + 1 : it;
        const float* zn = zbase + (size_t)itn * rowstride;
        f32x4 n0 = *(const f32x4*)(zn);
        f32x4 n1 = *(const f32x4*)(zn + 4);
        f32x4 n2 = *(const f32x4*)(zn + 32);
        f32x4 n3 = *(const f32x4*)(zn + 36);

        union { bf16x8 v; unsigned u[4]; } a0, a1;
        a0.u[0] = pkbf(c0[0], c0[1]); a0.u[1] = pkbf(c0[2], c0[3]);
        a0.u[2] = pkbf(c1[0], c1[1]); a0.u[3] = pkbf(c1[2], c1[3]);
        a1.u[0] = pkbf(c2[0], c2[1]); a1.u[1] = pkbf(c2[2], c2[3]);
        a1.u[2] = pkbf(c3[0], c3[1]); a1.u[3] = pkbf(c3[2], c3[3]);

        // scores for 16 rows x this wave's 128 codes; running argmax with
        // code index packed into low 10 mantissa bits
        f32x4 run;
        run[0] = run[1] = run[2] = run[3] = -1e30f;
        #pragma unroll
        for (int t = 0; t < 8; ++t) {
            f32x4 acc;
            acc[0] = acc[1] = acc[2] = acc[3] = bias[t];
            acc = __builtin_amdgcn_mfma_f32_16x16x32_bf16(a0.v, bfrag[t][0], acc, 0, 0, 0);
            acc = __builtin_amdgcn_mfma_f32_16x16x32_bf16(a1.v, bfrag[t][1], acc, 0, 0, 0);
            const unsigned idx = codebase + (unsigned)(t * 16);
            #pragma unroll
            for (int j = 0; j < 4; ++j) {
                float pf = __uint_as_float((__float_as_uint(acc[j]) & 0xFFFFFC00u) | idx);
                run[j] = fmaxf(run[j], pf);
            }
        }
        // 16-lane reduce (rows krow*4+j handled in parallel across j)
        #pragma unroll
        for (int j = 0; j < 4; ++j) {
            run[j] = dpp_max_step<0xB1>(run[j]);    // quad_perm xor1
            run[j] = dpp_max_step<0x4E>(run[j]);    // quad_perm xor2
            run[j] = dpp_max_step<0x124>(run[j]);   // row_ror:4
            run[j] = dpp_max_step<0x128>(run[j]);   // row_ror:8
        }
        if (col == 0)
            *(f32x4*)&wbest[it][w][krow * 4] = run;

        c0 = n0; c1 = n1; c2 = n2; c3 = n3;
    }

    __syncthreads();   // the ONLY inter-phase barrier

    // ---- Phase 2: epilogue — wave w owns tile it=w (16 rows), fully parallel
    float lossacc = 0.f;
    {
        const int rowbase2 = blockIdx.x * RPB + w * 16;
        const int rr = l & 15;
        float bb = wbest[w][0][rr];
        #pragma unroll
        for (int wv = 1; wv < 8; ++wv) bb = fmaxf(bb, wbest[w][wv][rr]);
        const int codeAll = (int)(__float_as_uint(bb) & 0x3FFu);
        const int myrow = l >> 2;           // 0..15
        const int sub   = l & 3;            // 16-float chunk within the row
        const int mycode = __shfl(codeAll, myrow, 64);

        const float* ep = cb + (size_t)mycode * D + sub * 16;
        const float* zp = z + (size_t)(rowbase2 + myrow) * D + sub * 16;
        float*       op = zq + (size_t)(rowbase2 + myrow) * D + sub * 16;
        #pragma unroll
        for (int q = 0; q < 4; ++q) {
            f32x4 ev = *(const f32x4*)(ep + q * 4);
            f32x4 zv = *(const f32x4*)(zp + q * 4);
            #pragma unroll
            for (int j = 0; j < 4; ++j) {
                const float dd = ev[j] - zv[j];
                lossacc = fmaf(dd, dd, lossacc);
            }
            *(f32x4*)(op + q * 4) = ev;
        }
    }

    // ---- loss: wave reduce -> LDS -> single atomic per block
    #pragma unroll
    for (int m = 1; m <= 32; m <<= 1)
        lossacc += __shfl_xor(lossacc, m, 64);
    if (l == 0) lossred[w] = lossacc;
    __syncthreads();
    if (tid == 0) {
        float s = 0.f;
        #pragma unroll
        for (int wv = 0; wv < 8; ++wv) s += lossred[wv];
        atomicAdd(lossp, s * (1.25f / (float)TOTAL_ELEM));
    }
}

extern "C" void kernel_launch(void* const* d_in, const int* in_sizes, int n_in,
                              void* d_out, int out_size, void* d_ws, size_t ws_size,
                              hipStream_t stream) {
    const float* z  = (const float*)d_in[0];
    const float* cb = (const float*)d_in[1];
    float* zq   = (float*)d_out;
    float* loss = zq + TOTAL_ELEM;   // scalar loss is the last output element
    hipMemsetAsync(loss, 0, sizeof(float), stream);
    vq_kernel<<<NBLK, 512, 0, stream>>>(z, cb, zq, loss);
}

// Round 11
// 187.776 us; speedup vs baseline: 1.0090x; 1.0090x over previous
//
#include <hip/hip_runtime.h>
#include <hip/hip_bf16.h>

#define D          64
#define N_ROWS     131072
#define TOTAL_ELEM (N_ROWS * D)      // 8388608
#define RPB        128               // rows per block
#define ITERS      (RPB / 16)        // 8
#define NBLK       (N_ROWS / RPB)    // 1024

typedef __attribute__((ext_vector_type(4))) float f32x4;
typedef __attribute__((ext_vector_type(8))) short bf16x8;

// pack two fp32 -> two bf16 (truncation) in one v_perm_b32
__device__ __forceinline__ unsigned pkbf(float lo, float hi) {
    return __builtin_amdgcn_perm(__float_as_uint(hi), __float_as_uint(lo), 0x07060302u);
}

// max with DPP-shifted copy (16-lane-row reduce, VALU pipe — no LDS traffic)
template <int CTRL>
__device__ __forceinline__ float dpp_max_step(float x) {
    int y = __builtin_amdgcn_update_dpp(0, __float_as_int(x), CTRL, 0xF, 0xF, false);
    return fmaxf(x, __int_as_float(y));
}

__global__ __launch_bounds__(512, 4)
void vq_kernel(const float* __restrict__ z, const float* __restrict__ cb,
               float* __restrict__ zq, float* __restrict__ lossp) {
    const int tid  = threadIdx.x;
    const int l    = tid & 63;
    const int w    = tid >> 6;      // wave 0..7 owns codes [w*128, w*128+128)
    const int col  = l & 15;
    const int krow = l >> 4;        // 0..3

    __shared__ float wbest[ITERS][8][16];   // [tile][wave][row] packed (score|idx)
    __shared__ float znorm[ITERS][16];      // [tile][row]  ||z_row||^2 (fp32)
    __shared__ float lossred[8];

    // ---- Phase 0: codebook -> register B-fragments + biases (-||e||^2/2) ----
    bf16x8 bfrag[8][2];
    float  bias[8];
    #pragma unroll
    for (int t = 0; t < 8; ++t) {
        const int code = (w * 8 + t) * 16 + col;
        const float* e = cb + code * D + krow * 8;
        f32x4 e0 = *(const f32x4*)(e);
        f32x4 e1 = *(const f32x4*)(e + 4);
        f32x4 e2 = *(const f32x4*)(e + 32);
        f32x4 e3 = *(const f32x4*)(e + 36);
        float np = 0.f;
        #pragma unroll
        for (int j = 0; j < 4; ++j) {
            np = fmaf(e0[j], e0[j], np); np = fmaf(e1[j], e1[j], np);
            np = fmaf(e2[j], e2[j], np); np = fmaf(e3[j], e3[j], np);
        }
        // sum the 4 lanes (l, l^16, l^32, l^48) holding this code's K-slices
        np += __shfl_xor(np, 16, 64);
        np += __shfl_xor(np, 32, 64);
        bias[t] = -0.5f * np;
        union { bf16x8 v; unsigned u[4]; } b0, b1;
        b0.u[0] = pkbf(e0[0], e0[1]); b0.u[1] = pkbf(e0[2], e0[3]);
        b0.u[2] = pkbf(e1[0], e1[1]); b0.u[3] = pkbf(e1[2], e1[3]);
        b1.u[0] = pkbf(e2[0], e2[1]); b1.u[1] = pkbf(e2[2], e2[3]);
        b1.u[2] = pkbf(e3[0], e3[1]); b1.u[3] = pkbf(e3[2], e3[3]);
        bfrag[t][0] = b0.v; bfrag[t][1] = b1.v;
    }

    const unsigned codebase = (unsigned)(w * 128 + col);

    // ---- Phase 1: scoring with 1-tile-ahead prefetch, NO barriers ----
    const size_t rowstride = (size_t)16 * D;
    const float* zbase = z + (size_t)(blockIdx.x * RPB + col) * D + krow * 8;
    f32x4 c0 = *(const f32x4*)(zbase);
    f32x4 c1 = *(const f32x4*)(zbase + 4);
    f32x4 c2 = *(const f32x4*)(zbase + 32);
    f32x4 c3 = *(const f32x4*)(zbase + 36);

    #pragma unroll 2
    for (int it = 0; it < ITERS; ++it) {
        // issue next tile's loads FIRST — latency hides under this tile's compute
        const int itn = (it + 1 < ITERS) ? it + 1 : it;
        const float* zn = zbase + (size_t)itn * rowstride;
        f32x4 n0 = *(const f32x4*)(zn);
        f32x4 n1 = *(const f32x4*)(zn + 4);
        f32x4 n2 = *(const f32x4*)(zn + 32);
        f32x4 n3 = *(const f32x4*)(zn + 36);

        // ||z_row||^2 in fp32 while z is live in registers (for the loss identity)
        float zs = 0.f;
        #pragma unroll
        for (int j = 0; j < 4; ++j) {
            zs = fmaf(c0[j], c0[j], zs); zs = fmaf(c1[j], c1[j], zs);
            zs = fmaf(c2[j], c2[j], zs); zs = fmaf(c3[j], c3[j], zs);
        }
        zs += __shfl_xor(zs, 16, 64);
        zs += __shfl_xor(zs, 32, 64);
        if (w == 0 && krow == 0) znorm[it][col] = zs;   // one wave suffices

        union { bf16x8 v; unsigned u[4]; } a0, a1;
        a0.u[0] = pkbf(c0[0], c0[1]); a0.u[1] = pkbf(c0[2], c0[3]);
        a0.u[2] = pkbf(c1[0], c1[1]); a0.u[3] = pkbf(c1[2], c1[3]);
        a1.u[0] = pkbf(c2[0], c2[1]); a1.u[1] = pkbf(c2[2], c2[3]);
        a1.u[2] = pkbf(c3[0], c3[1]); a1.u[3] = pkbf(c3[2], c3[3]);

        // scores for 16 rows x this wave's 128 codes; running argmax with
        // code index packed into low 10 mantissa bits
        f32x4 run;
        run[0] = run[1] = run[2] = run[3] = -1e30f;
        #pragma unroll
        for (int t = 0; t < 8; ++t) {
            f32x4 acc;
            acc[0] = acc[1] = acc[2] = acc[3] = bias[t];
            acc = __builtin_amdgcn_mfma_f32_16x16x32_bf16(a0.v, bfrag[t][0], acc, 0, 0, 0);
            acc = __builtin_amdgcn_mfma_f32_16x16x32_bf16(a1.v, bfrag[t][1], acc, 0, 0, 0);
            const unsigned idx = codebase + (unsigned)(t * 16);
            #pragma unroll
            for (int j = 0; j < 4; ++j) {
                float pf = __uint_as_float((__float_as_uint(acc[j]) & 0xFFFFFC00u) | idx);
                run[j] = fmaxf(run[j], pf);
            }
        }
        // 16-lane reduce (rows krow*4+j handled in parallel across j)
        #pragma unroll
        for (int j = 0; j < 4; ++j) {
            run[j] = dpp_max_step<0xB1>(run[j]);    // quad_perm xor1
            run[j] = dpp_max_step<0x4E>(run[j]);    // quad_perm xor2
            run[j] = dpp_max_step<0x124>(run[j]);   // row_ror:4
            run[j] = dpp_max_step<0x128>(run[j]);   // row_ror:8
        }
        if (col == 0)
            *(f32x4*)&wbest[it][w][krow * 4] = run;

        c0 = n0; c1 = n1; c2 = n2; c3 = n3;
    }

    __syncthreads();   // the ONLY inter-phase barrier

    // ---- Phase 2: epilogue — wave w owns tile it=w. NO z re-read:
    // dist_row = ||z||^2 - 2*score_clean  (score had -||e||^2/2 folded in)
    float lossacc = 0.f;
    {
        const int rowbase2 = blockIdx.x * RPB + w * 16;
        const int rr = l & 15;
        float bb = wbest[w][0][rr];
        #pragma unroll
        for (int wv = 1; wv < 8; ++wv) bb = fmaxf(bb, wbest[w][wv][rr]);
        const unsigned bbu = __float_as_uint(bb);
        const int   code_rr   = (int)(bbu & 0x3FFu);
        const float score_cln = __uint_as_float(bbu & 0xFFFFFC00u);

        if (l < 16)
            lossacc = znorm[w][rr] - 2.0f * score_cln;   // lanes 0..15: one row each

        const int myrow  = l >> 2;          // 0..15
        const int sub    = l & 3;           // 16-float chunk within the row
        const int mycode = __shfl(code_rr, myrow, 64);

        const float* ep = cb + (size_t)mycode * D + sub * 16;
        float*       op = zq + (size_t)(rowbase2 + myrow) * D + sub * 16;
        #pragma unroll
        for (int q = 0; q < 4; ++q) {
            f32x4 ev = *(const f32x4*)(ep + q * 4);
            *(f32x4*)(op + q * 4) = ev;
        }
    }

    // ---- loss: wave reduce -> LDS -> single atomic per block
    #pragma unroll
    for (int m = 1; m <= 32; m <<= 1)
        lossacc += __shfl_xor(lossacc, m, 64);
    if (l == 0) lossred[w] = lossacc;
    __syncthreads();
    if (tid == 0) {
        float s = 0.f;
        #pragma unroll
        for (int wv = 0; wv < 8; ++wv) s += lossred[wv];
        atomicAdd(lossp, s * (1.25f / (float)TOTAL_ELEM));
    }
}

extern "C" void kernel_launch(void* const* d_in, const int* in_sizes, int n_in,
                              void* d_out, int out_size, void* d_ws, size_t ws_size,
                              hipStream_t stream) {
    const float* z  = (const float*)d_in[0];
    const float* cb = (const float*)d_in[1];
    float* zq   = (float*)d_out;
    float* loss = zq + TOTAL_ELEM;   // scalar loss is the last output element
    hipMemsetAsync(loss, 0, sizeof(float), stream);
    vq_kernel<<<NBLK, 512, 0, stream>>>(z, cb, zq, loss);
}

// Round 12
// 141.711 us; speedup vs baseline: 1.3369x; 1.3251x over previous
//
#include <hip/hip_runtime.h>
#include <hip/hip_bf16.h>

#define D          64
#define N_ROWS     131072
#define TOTAL_ELEM (N_ROWS * D)      // 8388608
#define RPB        128               // rows per block
#define ITERS      (RPB / 16)        // 8
#define NBLK       (N_ROWS / RPB)    // 1024

typedef __attribute__((ext_vector_type(4))) float f32x4;
typedef __attribute__((ext_vector_type(8))) short bf16x8;

// pack two fp32 -> two bf16 (truncation) in one v_perm_b32
__device__ __forceinline__ unsigned pkbf(float lo, float hi) {
    return __builtin_amdgcn_perm(__float_as_uint(hi), __float_as_uint(lo), 0x07060302u);
}

// max with DPP-shifted copy (16-lane-row reduce, VALU pipe)
template <int CTRL>
__device__ __forceinline__ float dpp_max_step(float x) {
    int y = __builtin_amdgcn_update_dpp(0, __float_as_int(x), CTRL, 0xF, 0xF, false);
    return fmaxf(x, __int_as_float(y));
}

// async global->LDS, 16B per lane; dest = uniform base + lane*16 (HW rule)
__device__ __forceinline__ void gload_lds16(const void* g, void* l) {
    __builtin_amdgcn_global_load_lds(
        (const __attribute__((address_space(1))) void*)g,
        (__attribute__((address_space(3))) void*)l, 16, 0, 0);
}

__global__ __launch_bounds__(512, 4)
void vq_kernel(const float* __restrict__ z, const float* __restrict__ cb,
               float* __restrict__ zq, float* __restrict__ lossp) {
    const int tid  = threadIdx.x;
    const int l    = tid & 63;
    const int w    = tid >> 6;      // wave 0..7 owns codes [w*128, w*128+128)
    const int r    = l & 15;        // row-in-tile (A) / code-col (B)
    const int krow = l >> 4;        // k-slice 0..3

    // z staged once per block; 16B granule g of row rr stored at slot g^(rr&15)
    __shared__ __align__(16) char  zsl[RPB * 256];      // 32 KB
    __shared__ float wbest[ITERS][8][16];               // packed (score|idx)
    __shared__ float znrm[ITERS][16];                   // ||z_row||^2
    __shared__ float lossred[8];

    // ---- issue z staging FIRST; latency hides under codebook prep ----
    {
        const char* gtile = (const char*)(z + (size_t)(blockIdx.x * RPB + w * 16) * D);
        #pragma unroll
        for (int m = 0; m < 4; ++m) {
            const int rl = m * 4 + krow;            // row in this wave's tile
            const int gb = (r ^ rl) << 4;           // inverse-swizzled source granule
            gload_lds16(gtile + rl * 256 + gb, zsl + w * 4096 + m * 1024);
        }
    }

    // ---- Phase 0: codebook -> register B-fragments + biases (-||e||^2/2) ----
    bf16x8 bfrag[8][2];
    float  bias[8];
    #pragma unroll
    for (int t = 0; t < 8; ++t) {
        const int code = (w * 8 + t) * 16 + r;
        const float* e = cb + code * D + krow * 8;
        f32x4 e0 = *(const f32x4*)(e);
        f32x4 e1 = *(const f32x4*)(e + 4);
        f32x4 e2 = *(const f32x4*)(e + 32);
        f32x4 e3 = *(const f32x4*)(e + 36);
        float np = 0.f;
        #pragma unroll
        for (int j = 0; j < 4; ++j) {
            np = fmaf(e0[j], e0[j], np); np = fmaf(e1[j], e1[j], np);
            np = fmaf(e2[j], e2[j], np); np = fmaf(e3[j], e3[j], np);
        }
        np += __shfl_xor(np, 16, 64);
        np += __shfl_xor(np, 32, 64);
        bias[t] = -0.5f * np;
        union { bf16x8 v; unsigned u[4]; } b0, b1;
        b0.u[0] = pkbf(e0[0], e0[1]); b0.u[1] = pkbf(e0[2], e0[3]);
        b0.u[2] = pkbf(e1[0], e1[1]); b0.u[3] = pkbf(e1[2], e1[3]);
        b1.u[0] = pkbf(e2[0], e2[1]); b1.u[1] = pkbf(e2[2], e2[3]);
        b1.u[2] = pkbf(e3[0], e3[1]); b1.u[3] = pkbf(e3[2], e3[3]);
        bfrag[t][0] = b0.v; bfrag[t][1] = b1.v;
    }

    asm volatile("s_waitcnt vmcnt(0)" ::: "memory");
    __syncthreads();

    const unsigned codebase = (unsigned)(w * 128 + r);

    // ---- Phase 1: scoring, all-LDS A-reads, no global traffic ----
    #pragma unroll 2
    for (int it = 0; it < ITERS; ++it) {
        const char* zl = zsl + (it * 16 + r) * 256;
        f32x4 z0 = *(const f32x4*)(zl + (((2 * krow    ) ^ r) << 4));
        f32x4 z1 = *(const f32x4*)(zl + (((2 * krow + 1) ^ r) << 4));
        f32x4 z2 = *(const f32x4*)(zl + (((2 * krow + 8) ^ r) << 4));
        f32x4 z3 = *(const f32x4*)(zl + (((2 * krow + 9) ^ r) << 4));

        // ||z_row||^2 (for the loss identity)
        float zs = 0.f;
        #pragma unroll
        for (int j = 0; j < 4; ++j) {
            zs = fmaf(z0[j], z0[j], zs); zs = fmaf(z1[j], z1[j], zs);
            zs = fmaf(z2[j], z2[j], zs); zs = fmaf(z3[j], z3[j], zs);
        }
        zs += __shfl_xor(zs, 16, 64);
        zs += __shfl_xor(zs, 32, 64);
        if (w == 0 && krow == 0) znrm[it][r] = zs;

        union { bf16x8 v; unsigned u[4]; } a0, a1;
        a0.u[0] = pkbf(z0[0], z0[1]); a0.u[1] = pkbf(z0[2], z0[3]);
        a0.u[2] = pkbf(z1[0], z1[1]); a0.u[3] = pkbf(z1[2], z1[3]);
        a1.u[0] = pkbf(z2[0], z2[1]); a1.u[1] = pkbf(z2[2], z2[3]);
        a1.u[2] = pkbf(z3[0], z3[1]); a1.u[3] = pkbf(z3[2], z3[3]);

        f32x4 run;
        run[0] = run[1] = run[2] = run[3] = -1e30f;
        #pragma unroll
        for (int t = 0; t < 8; ++t) {
            f32x4 acc;
            acc[0] = acc[1] = acc[2] = acc[3] = bias[t];
            acc = __builtin_amdgcn_mfma_f32_16x16x32_bf16(a0.v, bfrag[t][0], acc, 0, 0, 0);
            acc = __builtin_amdgcn_mfma_f32_16x16x32_bf16(a1.v, bfrag[t][1], acc, 0, 0, 0);
            const unsigned idx = codebase + (unsigned)(t * 16);
            #pragma unroll
            for (int j = 0; j < 4; ++j) {
                float pf = __uint_as_float((__float_as_uint(acc[j]) & 0xFFFFFC00u) | idx);
                run[j] = fmaxf(run[j], pf);
            }
        }
        #pragma unroll
        for (int j = 0; j < 4; ++j) {
            run[j] = dpp_max_step<0xB1>(run[j]);
            run[j] = dpp_max_step<0x4E>(run[j]);
            run[j] = dpp_max_step<0x124>(run[j]);
            run[j] = dpp_max_step<0x128>(run[j]);
        }
        if (r == 0)
            *(f32x4*)&wbest[it][w][krow * 4] = run;
    }

    __syncthreads();

    // ---- Phase 2: wave w owns tile w. Loss from identity; contiguous stores.
    float lossacc = 0.f;
    {
        const int rowbase2 = blockIdx.x * RPB + w * 16;
        float bb = wbest[w][0][r];
        #pragma unroll
        for (int wv = 1; wv < 8; ++wv) bb = fmaxf(bb, wbest[w][wv][r]);
        const unsigned bbu = __float_as_uint(bb);
        const int   code_rr   = (int)(bbu & 0x3FFu);
        const float score_cln = __uint_as_float(bbu & 0xFFFFFC00u);

        if (l < 16)
            lossacc = znrm[w][r] - 2.0f * score_cln;   // lanes 0..15: one row each

        // instr q writes rows q*4..q*4+3 — 1 KB contiguous per instruction
        float* opbase = zq + (size_t)rowbase2 * D;
        #pragma unroll
        for (int q = 0; q < 4; ++q) {
            const int row4   = q * 4 + krow;
            const int mycode = __shfl(code_rr, row4, 64);
            f32x4 ev = *(const f32x4*)(cb + (size_t)mycode * D + r * 4);
            *(f32x4*)(opbase + row4 * D + r * 4) = ev;
        }
    }

    // ---- loss: wave reduce -> LDS -> single atomic per block
    #pragma unroll
    for (int m = 1; m <= 32; m <<= 1)
        lossacc += __shfl_xor(lossacc, m, 64);
    if (l == 0) lossred[w] = lossacc;
    __syncthreads();
    if (tid == 0) {
        float s = 0.f;
        #pragma unroll
        for (int wv = 0; wv < 8; ++wv) s += lossred[wv];
        atomicAdd(lossp, s * (1.25f / (float)TOTAL_ELEM));
    }
}

extern "C" void kernel_launch(void* const* d_in, const int* in_sizes, int n_in,
                              void* d_out, int out_size, void* d_ws, size_t ws_size,
                              hipStream_t stream) {
    const float* z  = (const float*)d_in[0];
    const float* cb = (const float*)d_in[1];
    float* zq   = (float*)d_out;
    float* loss = zq + TOTAL_ELEM;   // scalar loss is the last output element
    hipMemsetAsync(loss, 0, sizeof(float), stream);
    vq_kernel<<<NBLK, 512, 0, stream>>>(z, cb, zq, loss);
}